// Round 6
// baseline (369.457 us; speedup 1.0000x reference)
//
#include <hip/hip_runtime.h>

#define TEMP 5.656854249492380195f   // sqrt(32)
#define EPSG 1e-10f

// ---------- K1: per-b projection + pair argmax + hmean; block0 also does
// ----------     k2f precompute + bucket-counter zeroing (merged K0) -------
__launch_bounds__(256, 4)
__global__ void k1_kernel(const float* __restrict__ hidden,
                          const float* __restrict__ u_var,
                          const float* __restrict__ Wq,
                          const float* __restrict__ bq,
                          const float* __restrict__ Wk,
                          const float* __restrict__ bk,
                          const float* __restrict__ rule_emb,
                          const float* __restrict__ Wk2,
                          const float* __restrict__ bk2,
                          float* __restrict__ k2f,
                          int* __restrict__ cnt,
                          int* __restrict__ selbuf,
                          float* __restrict__ outbuf) {
    const int tid = threadIdx.x;
    const int b   = blockIdx.x;

    __shared__ float sh[4096];          // hidden[b] (16 KB)
    __shared__ float s_qk[2][8][32];    // [q/k][v][d]

    // merged K0 (block 0 only): k2 = rule_emb@Wk2 + bk2 ; cnt = 0
    if (b == 0) {
        if (tid < 16) cnt[tid] = 0;
        for (int t = tid; t < 512; t += 256) {
            int r = t >> 5, d = t & 31;
            float acc = bk2[d];
            for (int h = 0; h < 64; ++h)
                acc += rule_emb[r * 64 + h] * Wk2[h * 32 + d];
            k2f[t] = acc;
        }
    }

    // stage hidden[b]
    const float* hb = hidden + (size_t)b * 4096;
    #pragma unroll
    for (int c = 0; c < 4; ++c)
        *reinterpret_cast<float4*>(&sh[c * 1024 + tid * 4]) =
            *reinterpret_cast<const float4*>(hb + c * 1024 + tid * 4);
    __syncthreads();

    // projection: thread = (qk, dg(4 cols), sl(16 K-slices)); weights
    // streamed from L2 as float4 (reused across 8 v), FP order identical
    // to the previously-passing kernel.
    {
        const int qk = tid >> 7;
        const int dg = (tid >> 4) & 7;
        const int sl = tid & 15;
        const float* Wsrc = (qk ? Wk : Wq) + dg * 4;

        float4 acc[8];
        #pragma unroll
        for (int v = 0; v < 8; ++v) acc[v] = make_float4(0.f, 0.f, 0.f, 0.f);

        #pragma unroll
        for (int i = 0; i < 8; ++i) {
            const float* wrow = Wsrc + (size_t)(i * 64 + sl * 4) * 32;
            float4 w0 = *reinterpret_cast<const float4*>(wrow);
            float4 w1 = *reinterpret_cast<const float4*>(wrow + 32);
            float4 w2 = *reinterpret_cast<const float4*>(wrow + 64);
            float4 w3 = *reinterpret_cast<const float4*>(wrow + 96);
            #pragma unroll
            for (int v = 0; v < 8; ++v) {
                float4 x = *reinterpret_cast<const float4*>(&sh[v * 512 + i * 64 + sl * 4]);
                acc[v].x += x.x * w0.x + x.y * w1.x + x.z * w2.x + x.w * w3.x;
                acc[v].y += x.x * w0.y + x.y * w1.y + x.z * w2.y + x.w * w3.y;
                acc[v].z += x.x * w0.z + x.y * w1.z + x.z * w2.z + x.w * w3.z;
                acc[v].w += x.x * w0.w + x.y * w1.w + x.z * w2.w + x.w * w3.w;
            }
        }
        #pragma unroll
        for (int off = 1; off < 16; off <<= 1) {
            #pragma unroll
            for (int v = 0; v < 8; ++v) {
                acc[v].x += __shfl_xor(acc[v].x, off);
                acc[v].y += __shfl_xor(acc[v].y, off);
                acc[v].z += __shfl_xor(acc[v].z, off);
                acc[v].w += __shfl_xor(acc[v].w, off);
            }
        }
        if (sl == 0) {
            const float* bsrc = (qk ? bk : bq) + dg * 4;
            float4 bias4 = *reinterpret_cast<const float4*>(bsrc);
            #pragma unroll
            for (int v = 0; v < 8; ++v) {
                float4 r;
                r.x = acc[v].x + bias4.x; r.y = acc[v].y + bias4.y;
                r.z = acc[v].z + bias4.z; r.w = acc[v].w + bias4.w;
                *reinterpret_cast<float4*>(&s_qk[qk][v][dg * 4]) = r;
            }
        }
    }

    // hmean -> outbuf[b][0..511] (scratch; K3 later overwrites all of out)
    {
        int h2 = tid * 2;
        float m0 = 0.f, m1 = 0.f;
        #pragma unroll
        for (int v = 0; v < 8; ++v) {
            float2 x2 = *reinterpret_cast<const float2*>(&sh[v * 512 + h2]);
            m0 += x2.x; m1 += x2.y;
        }
        float2 mo; mo.x = m0 * 0.125f; mo.y = m1 * 0.125f;
        *reinterpret_cast<float2*>(outbuf + (size_t)b * 4096 + h2) = mo;
    }
    __syncthreads();

    // wave 0: scores + gumbel + 64-way argmax -> selbuf[b]
    if (tid < 64) {
        int i = tid >> 3, j = tid & 7;
        float s = 0.f;
        #pragma unroll
        for (int d4 = 0; d4 < 8; ++d4) {
            float4 qv = *reinterpret_cast<const float4*>(&s_qk[0][i][d4 * 4]);
            float4 kv = *reinterpret_cast<const float4*>(&s_qk[1][j][d4 * 4]);
            s += qv.x * kv.x + qv.y * kv.y + qv.z * kv.z + qv.w * kv.w;
        }
        s /= TEMP;
        float u = u_var[(size_t)b * 64 + tid];
        float g = -logf(-logf(u + EPSG) + EPSG);
        float pm = s + g;
        int idx = tid;
        #pragma unroll
        for (int off = 32; off >= 1; off >>= 1) {
            float pv = __shfl_xor(pm, off);
            int   pi = __shfl_xor(idx, off);
            if (pv > pm || (pv == pm && pi < idx)) { pm = pv; idx = pi; }
        }
        if (tid == 0) selbuf[b] = idx;
    }
}

// ---------- K2: q2 GEMM + rule gumbel argmax + rule buckets ----------------
__launch_bounds__(256, 4)
__global__ void k2sel_kernel(const float* __restrict__ hidden,
                             const float* __restrict__ u_rule,
                             const float* __restrict__ Wq2,
                             const float* __restrict__ bq2,
                             const float* __restrict__ k2f,
                             const int* __restrict__ selbuf,
                             const float* __restrict__ hmeanbuf,
                             int* __restrict__ cnt,
                             int* __restrict__ list) {
    const int tid = threadIdx.x;
    const int b0 = blockIdx.x * 8;

    __shared__ float  s_k2[512];
    __shared__ float  xt[8][256];
    __shared__ float4 part4[4][8][8];
    __shared__ float  s_q2[8][32];
    __shared__ int    s_sel8[8];

    s_k2[tid]       = k2f[tid];
    s_k2[tid + 256] = k2f[tid + 256];
    if (tid < 8) s_sel8[tid] = selbuf[b0 + tid];
    __syncthreads();

    const int d4 = tid & 7, s = tid >> 3;
    float4 acc[8];
    #pragma unroll
    for (int bb = 0; bb < 8; ++bb) acc[bb] = make_float4(0.f, 0.f, 0.f, 0.f);

    for (int kt = 0; kt < 6; ++kt) {
        float4 w[8];
        #pragma unroll
        for (int j = 0; j < 8; ++j)
            w[j] = *reinterpret_cast<const float4*>(Wq2 + (size_t)(kt * 256 + s * 8 + j) * 32 + d4 * 4);
        #pragma unroll
        for (int bb = 0; bb < 8; ++bb) {
            const int b  = b0 + bb;
            const int sv = s_sel8[bb];
            const float* src;
            if (kt < 2)      src = hidden  + ((size_t)b * 8 + (sv & 7))  * 512 + kt * 256;
            else if (kt < 4) src = hidden  + ((size_t)b * 8 + (sv >> 3)) * 512 + (kt - 2) * 256;
            else             src = hmeanbuf + (size_t)b * 4096 + (kt - 4) * 256;
            xt[bb][tid] = src[tid];
        }
        __syncthreads();
        #pragma unroll
        for (int bb = 0; bb < 8; ++bb) {
            #pragma unroll
            for (int j = 0; j < 8; ++j) {
                float x = xt[bb][s * 8 + j];
                acc[bb].x += x * w[j].x;
                acc[bb].y += x * w[j].y;
                acc[bb].z += x * w[j].z;
                acc[bb].w += x * w[j].w;
            }
        }
        __syncthreads();
    }
    #pragma unroll
    for (int off = 8; off < 64; off <<= 1) {
        #pragma unroll
        for (int bb = 0; bb < 8; ++bb) {
            acc[bb].x += __shfl_xor(acc[bb].x, off);
            acc[bb].y += __shfl_xor(acc[bb].y, off);
            acc[bb].z += __shfl_xor(acc[bb].z, off);
            acc[bb].w += __shfl_xor(acc[bb].w, off);
        }
    }
    if ((s & 7) == 0) {
        #pragma unroll
        for (int bb = 0; bb < 8; ++bb) part4[tid >> 6][bb][d4] = acc[bb];
    }
    __syncthreads();
    {
        const int bb = tid >> 5, col = tid & 31;
        float q2 = bq2[col];
        #pragma unroll
        for (int wv = 0; wv < 4; ++wv) {
            const float* pf = reinterpret_cast<const float*>(&part4[wv][bb][col >> 2]);
            q2 += pf[col & 3];
        }
        s_q2[bb][col] = q2;
    }
    __syncthreads();
    if (tid < 128) {
        const int bb = tid >> 4, r = tid & 15;
        const int b = b0 + bb;
        float sc = 0.f;
        #pragma unroll
        for (int d = 0; d < 32; ++d) sc += s_q2[bb][d] * s_k2[r * 32 + d];
        sc /= TEMP;
        float u = u_rule[(size_t)b * 16 + r];
        float g = -logf(-logf(u + EPSG) + EPSG);
        float pm = sc + g;
        int idx = r;
        #pragma unroll
        for (int off = 8; off >= 1; off >>= 1) {
            float pv = __shfl_xor(pm, off, 16);
            int   pi = __shfl_xor(idx, off, 16);
            if (pv > pm || (pv == pm && pi < idx)) { pm = pv; idx = pi; }
        }
        if (r == 0) {
            int pos = atomicAdd(&cnt[idx], 1);
            list[idx * 4096 + pos] = b;
        }
    }
}

// ---------- K3: rule-bucketed MLP + full output write ----------------------
__launch_bounds__(256, 2)
__global__ void k3_kernel(const float* __restrict__ hidden,
                          const float* __restrict__ W1,
                          const float* __restrict__ W2,
                          const int* __restrict__ selbuf,
                          const int* __restrict__ cnt,
                          const int* __restrict__ list,
                          float* __restrict__ outbuf) {
    const int tid = threadIdx.x;
    const int r   = blockIdx.x & 15;       // rule
    const int c   = blockIdx.x >> 4;       // chunk 0..31

    __shared__ float w1s[16384];           // W1[r] as [row*16+e] (64 KB)
    __shared__ float comb[1024];
    __shared__ float part[4][16];
    __shared__ float s_h1[16];

    #pragma unroll
    for (int i = 0; i < 16; ++i) {
        int idx = i * 1024 + tid * 4;
        *reinterpret_cast<float4*>(&w1s[idx]) =
            *reinterpret_cast<const float4*>(W1 + (size_t)r * 16384 + idx);
    }
    const int n = cnt[r];
    __syncthreads();

    const int e  = tid & 15;
    const int sl = tid >> 4;

    for (int idx = c; idx < n; idx += 32) {
        const int b  = list[r * 4096 + idx];
        const int sv = selbuf[b];
        const int js = sv & 7, cs = sv >> 3;

        {
            const float4* h4 = reinterpret_cast<const float4*>(hidden);
            float4 v;
            if (tid < 128) v = h4[((size_t)b * 8 + js) * 128 + tid];
            else           v = h4[((size_t)b * 8 + cs) * 128 + (tid - 128)];
            *reinterpret_cast<float4*>(&comb[tid * 4]) = v;
        }
        __syncthreads();

        float a = 0.f;
        for (int i = 0; i < 64; ++i) {
            int rr = i * 16 + sl;
            a += comb[rr] * w1s[rr * 16 + e];
        }
        a += __shfl_xor(a, 16);
        a += __shfl_xor(a, 32);
        if ((sl & 3) == 0) part[sl >> 2][e] = a;
        __syncthreads();
        if (tid < 16)
            s_h1[tid] = fmaxf(part[0][tid] + part[1][tid] + part[2][tid] + part[3][tid], 0.f);
        __syncthreads();

        const float* w2 = W2 + (size_t)r * 8192;
        int o0 = tid * 2;
        float a0 = 0.f, a1 = 0.f;
        #pragma unroll
        for (int ee = 0; ee < 16; ++ee) {
            float h1e = s_h1[ee];
            float2 ww = *reinterpret_cast<const float2*>(w2 + ee * 512 + o0);
            a0 += h1e * ww.x;
            a1 += h1e * ww.y;
        }
        float2 nz = make_float2(a0, a1);
        float2 zz = make_float2(0.f, 0.f);
        float2* ob = reinterpret_cast<float2*>(outbuf + (size_t)b * 4096);
        #pragma unroll
        for (int v = 0; v < 8; ++v)
            ob[v * 256 + tid] = (v == js) ? nz : zz;
    }
}

extern "C" void kernel_launch(void* const* d_in, const int* in_sizes, int n_in,
                              void* d_out, int out_size, void* d_ws, size_t ws_size,
                              hipStream_t stream) {
    const float* hidden   = (const float*)d_in[0];
    const float* u_var    = (const float*)d_in[1];
    const float* u_rule   = (const float*)d_in[2];
    const float* Wq       = (const float*)d_in[3];
    const float* bq       = (const float*)d_in[4];
    const float* Wk       = (const float*)d_in[5];
    const float* bk       = (const float*)d_in[6];
    const float* rule_emb = (const float*)d_in[7];
    const float* Wq2      = (const float*)d_in[8];
    const float* bq2      = (const float*)d_in[9];
    const float* Wk2      = (const float*)d_in[10];
    const float* bk2      = (const float*)d_in[11];
    const float* W1       = (const float*)d_in[12];
    const float* W2       = (const float*)d_in[13];

    char* ws = (char*)d_ws;
    float* k2f  = (float*)(ws);              // 512 f32
    int*   cnt  = (int*)(ws + 2048);         // 16 i32
    int*   sel  = (int*)(ws + 4096);         // 4096 i32
    int*   list = (int*)(ws + 20480);        // 16*4096 i32
    float* outf = (float*)d_out;

    hipLaunchKernelGGL(k1_kernel, dim3(4096), dim3(256), 0, stream,
                       hidden, u_var, Wq, bq, Wk, bk,
                       rule_emb, Wk2, bk2, k2f, cnt, sel, outf);
    hipLaunchKernelGGL(k2sel_kernel, dim3(512), dim3(256), 0, stream,
                       hidden, u_rule, Wq2, bq2, k2f, sel, outf, cnt, list);
    hipLaunchKernelGGL(k3_kernel, dim3(512), dim3(256), 0, stream,
                       hidden, W1, W2, sel, cnt, list, outf);
}

// Round 7
// 126.844 us; speedup vs baseline: 2.9127x; 2.9127x over previous
//
#include <hip/hip_runtime.h>

#define TEMP 5.656854249492380195f   // sqrt(32)
#define EPSG 1e-10f

// ---------- K1: per-b projection + pair argmax + hmean; block0 also does
// ----------     k2f precompute + bucket-counter zeroing (merged K0) -------
// launch_bounds (256,2): allow ~128 VGPRs. Round-6's (256,4) capped VGPR=64
// and spilled acc to scratch (732 MB WRITE_SIZE, VALUBusy 8%). unroll 2 keeps
// <=32 weight regs live.
__launch_bounds__(256, 2)
__global__ void k1_kernel(const float* __restrict__ hidden,
                          const float* __restrict__ u_var,
                          const float* __restrict__ Wq,
                          const float* __restrict__ bq,
                          const float* __restrict__ Wk,
                          const float* __restrict__ bk,
                          const float* __restrict__ rule_emb,
                          const float* __restrict__ Wk2,
                          const float* __restrict__ bk2,
                          float* __restrict__ k2f,
                          int* __restrict__ cnt,
                          int* __restrict__ selbuf,
                          float* __restrict__ outbuf) {
    const int tid = threadIdx.x;
    const int b   = blockIdx.x;

    __shared__ float sh[4096];          // hidden[b] (16 KB)
    __shared__ float s_qk[2][8][32];    // [q/k][v][d]

    // merged K0 (block 0 only): k2 = rule_emb@Wk2 + bk2 ; cnt = 0
    if (b == 0) {
        if (tid < 16) cnt[tid] = 0;
        for (int t = tid; t < 512; t += 256) {
            int r = t >> 5, d = t & 31;
            float acc = bk2[d];
            for (int h = 0; h < 64; ++h)
                acc += rule_emb[r * 64 + h] * Wk2[h * 32 + d];
            k2f[t] = acc;
        }
    }

    // stage hidden[b]
    const float* hb = hidden + (size_t)b * 4096;
    #pragma unroll
    for (int c = 0; c < 4; ++c)
        *reinterpret_cast<float4*>(&sh[c * 1024 + tid * 4]) =
            *reinterpret_cast<const float4*>(hb + c * 1024 + tid * 4);
    __syncthreads();

    // projection: thread = (qk, dg(4 cols), sl(16 K-slices)); weights
    // streamed from L2 as float4 (reused across 8 v). FP order identical
    // to the passing round-5 kernel.
    {
        const int qk = tid >> 7;
        const int dg = (tid >> 4) & 7;
        const int sl = tid & 15;
        const float* Wsrc = (qk ? Wk : Wq) + dg * 4;

        float4 acc[8];
        #pragma unroll
        for (int v = 0; v < 8; ++v) acc[v] = make_float4(0.f, 0.f, 0.f, 0.f);

        #pragma unroll 2
        for (int i = 0; i < 8; ++i) {
            const float* wrow = Wsrc + (size_t)(i * 64 + sl * 4) * 32;
            float4 w0 = *reinterpret_cast<const float4*>(wrow);
            float4 w1 = *reinterpret_cast<const float4*>(wrow + 32);
            float4 w2 = *reinterpret_cast<const float4*>(wrow + 64);
            float4 w3 = *reinterpret_cast<const float4*>(wrow + 96);
            #pragma unroll
            for (int v = 0; v < 8; ++v) {
                float4 x = *reinterpret_cast<const float4*>(&sh[v * 512 + i * 64 + sl * 4]);
                acc[v].x += x.x * w0.x + x.y * w1.x + x.z * w2.x + x.w * w3.x;
                acc[v].y += x.x * w0.y + x.y * w1.y + x.z * w2.y + x.w * w3.y;
                acc[v].z += x.x * w0.z + x.y * w1.z + x.z * w2.z + x.w * w3.z;
                acc[v].w += x.x * w0.w + x.y * w1.w + x.z * w2.w + x.w * w3.w;
            }
        }
        #pragma unroll
        for (int off = 1; off < 16; off <<= 1) {
            #pragma unroll
            for (int v = 0; v < 8; ++v) {
                acc[v].x += __shfl_xor(acc[v].x, off);
                acc[v].y += __shfl_xor(acc[v].y, off);
                acc[v].z += __shfl_xor(acc[v].z, off);
                acc[v].w += __shfl_xor(acc[v].w, off);
            }
        }
        if (sl == 0) {
            const float* bsrc = (qk ? bk : bq) + dg * 4;
            float4 bias4 = *reinterpret_cast<const float4*>(bsrc);
            #pragma unroll
            for (int v = 0; v < 8; ++v) {
                float4 r;
                r.x = acc[v].x + bias4.x; r.y = acc[v].y + bias4.y;
                r.z = acc[v].z + bias4.z; r.w = acc[v].w + bias4.w;
                *reinterpret_cast<float4*>(&s_qk[qk][v][dg * 4]) = r;
            }
        }
    }

    // hmean -> outbuf[b][0..511] (scratch; K3 later overwrites all of out)
    {
        int h2 = tid * 2;
        float m0 = 0.f, m1 = 0.f;
        #pragma unroll
        for (int v = 0; v < 8; ++v) {
            float2 x2 = *reinterpret_cast<const float2*>(&sh[v * 512 + h2]);
            m0 += x2.x; m1 += x2.y;
        }
        float2 mo; mo.x = m0 * 0.125f; mo.y = m1 * 0.125f;
        *reinterpret_cast<float2*>(outbuf + (size_t)b * 4096 + h2) = mo;
    }
    __syncthreads();

    // wave 0: scores + gumbel + 64-way argmax -> selbuf[b]
    if (tid < 64) {
        int i = tid >> 3, j = tid & 7;
        float s = 0.f;
        #pragma unroll
        for (int d4 = 0; d4 < 8; ++d4) {
            float4 qv = *reinterpret_cast<const float4*>(&s_qk[0][i][d4 * 4]);
            float4 kv = *reinterpret_cast<const float4*>(&s_qk[1][j][d4 * 4]);
            s += qv.x * kv.x + qv.y * kv.y + qv.z * kv.z + qv.w * kv.w;
        }
        s /= TEMP;
        float u = u_var[(size_t)b * 64 + tid];
        float g = -logf(-logf(u + EPSG) + EPSG);
        float pm = s + g;
        int idx = tid;
        #pragma unroll
        for (int off = 32; off >= 1; off >>= 1) {
            float pv = __shfl_xor(pm, off);
            int   pi = __shfl_xor(idx, off);
            if (pv > pm || (pv == pm && pi < idx)) { pm = pv; idx = pi; }
        }
        if (tid == 0) selbuf[b] = idx;
    }
}

// ---------- K2: q2 GEMM + rule gumbel argmax + rule buckets ----------------
__launch_bounds__(256, 4)
__global__ void k2sel_kernel(const float* __restrict__ hidden,
                             const float* __restrict__ u_rule,
                             const float* __restrict__ Wq2,
                             const float* __restrict__ bq2,
                             const float* __restrict__ k2f,
                             const int* __restrict__ selbuf,
                             const float* __restrict__ hmeanbuf,
                             int* __restrict__ cnt,
                             int* __restrict__ list) {
    const int tid = threadIdx.x;
    const int b0 = blockIdx.x * 8;

    __shared__ float  s_k2[512];
    __shared__ float  xt[8][256];
    __shared__ float4 part4[4][8][8];
    __shared__ float  s_q2[8][32];
    __shared__ int    s_sel8[8];

    s_k2[tid]       = k2f[tid];
    s_k2[tid + 256] = k2f[tid + 256];
    if (tid < 8) s_sel8[tid] = selbuf[b0 + tid];
    __syncthreads();

    const int d4 = tid & 7, s = tid >> 3;
    float4 acc[8];
    #pragma unroll
    for (int bb = 0; bb < 8; ++bb) acc[bb] = make_float4(0.f, 0.f, 0.f, 0.f);

    for (int kt = 0; kt < 6; ++kt) {
        float4 w[8];
        #pragma unroll
        for (int j = 0; j < 8; ++j)
            w[j] = *reinterpret_cast<const float4*>(Wq2 + (size_t)(kt * 256 + s * 8 + j) * 32 + d4 * 4);
        #pragma unroll
        for (int bb = 0; bb < 8; ++bb) {
            const int b  = b0 + bb;
            const int sv = s_sel8[bb];
            const float* src;
            if (kt < 2)      src = hidden  + ((size_t)b * 8 + (sv & 7))  * 512 + kt * 256;
            else if (kt < 4) src = hidden  + ((size_t)b * 8 + (sv >> 3)) * 512 + (kt - 2) * 256;
            else             src = hmeanbuf + (size_t)b * 4096 + (kt - 4) * 256;
            xt[bb][tid] = src[tid];
        }
        __syncthreads();
        #pragma unroll
        for (int bb = 0; bb < 8; ++bb) {
            #pragma unroll
            for (int j = 0; j < 8; ++j) {
                float x = xt[bb][s * 8 + j];
                acc[bb].x += x * w[j].x;
                acc[bb].y += x * w[j].y;
                acc[bb].z += x * w[j].z;
                acc[bb].w += x * w[j].w;
            }
        }
        __syncthreads();
    }
    #pragma unroll
    for (int off = 8; off < 64; off <<= 1) {
        #pragma unroll
        for (int bb = 0; bb < 8; ++bb) {
            acc[bb].x += __shfl_xor(acc[bb].x, off);
            acc[bb].y += __shfl_xor(acc[bb].y, off);
            acc[bb].z += __shfl_xor(acc[bb].z, off);
            acc[bb].w += __shfl_xor(acc[bb].w, off);
        }
    }
    if ((s & 7) == 0) {
        #pragma unroll
        for (int bb = 0; bb < 8; ++bb) part4[tid >> 6][bb][d4] = acc[bb];
    }
    __syncthreads();
    {
        const int bb = tid >> 5, col = tid & 31;
        float q2 = bq2[col];
        #pragma unroll
        for (int wv = 0; wv < 4; ++wv) {
            const float* pf = reinterpret_cast<const float*>(&part4[wv][bb][col >> 2]);
            q2 += pf[col & 3];
        }
        s_q2[bb][col] = q2;
    }
    __syncthreads();
    if (tid < 128) {
        const int bb = tid >> 4, r = tid & 15;
        const int b = b0 + bb;
        float sc = 0.f;
        #pragma unroll
        for (int d = 0; d < 32; ++d) sc += s_q2[bb][d] * s_k2[r * 32 + d];
        sc /= TEMP;
        float u = u_rule[(size_t)b * 16 + r];
        float g = -logf(-logf(u + EPSG) + EPSG);
        float pm = sc + g;
        int idx = r;
        #pragma unroll
        for (int off = 8; off >= 1; off >>= 1) {
            float pv = __shfl_xor(pm, off, 16);
            int   pi = __shfl_xor(idx, off, 16);
            if (pv > pm || (pv == pm && pi < idx)) { pm = pv; idx = pi; }
        }
        if (r == 0) {
            int pos = atomicAdd(&cnt[idx], 1);
            list[idx * 4096 + pos] = b;
        }
    }
}

// ---------- K3: rule-bucketed MLP + full output write ----------------------
__launch_bounds__(256, 2)
__global__ void k3_kernel(const float* __restrict__ hidden,
                          const float* __restrict__ W1,
                          const float* __restrict__ W2,
                          const int* __restrict__ selbuf,
                          const int* __restrict__ cnt,
                          const int* __restrict__ list,
                          float* __restrict__ outbuf) {
    const int tid = threadIdx.x;
    const int r   = blockIdx.x & 15;       // rule
    const int c   = blockIdx.x >> 4;       // chunk 0..31

    __shared__ float w1s[16384];           // W1[r] as [row*16+e] (64 KB)
    __shared__ float comb[1024];
    __shared__ float part[4][16];
    __shared__ float s_h1[16];

    #pragma unroll
    for (int i = 0; i < 16; ++i) {
        int idx = i * 1024 + tid * 4;
        *reinterpret_cast<float4*>(&w1s[idx]) =
            *reinterpret_cast<const float4*>(W1 + (size_t)r * 16384 + idx);
    }
    const int n = cnt[r];
    __syncthreads();

    const int e  = tid & 15;
    const int sl = tid >> 4;

    for (int idx = c; idx < n; idx += 32) {
        const int b  = list[r * 4096 + idx];
        const int sv = selbuf[b];
        const int js = sv & 7, cs = sv >> 3;

        {
            const float4* h4 = reinterpret_cast<const float4*>(hidden);
            float4 v;
            if (tid < 128) v = h4[((size_t)b * 8 + js) * 128 + tid];
            else           v = h4[((size_t)b * 8 + cs) * 128 + (tid - 128)];
            *reinterpret_cast<float4*>(&comb[tid * 4]) = v;
        }
        __syncthreads();

        float a = 0.f;
        for (int i = 0; i < 64; ++i) {
            int rr = i * 16 + sl;
            a += comb[rr] * w1s[rr * 16 + e];
        }
        a += __shfl_xor(a, 16);
        a += __shfl_xor(a, 32);
        if ((sl & 3) == 0) part[sl >> 2][e] = a;
        __syncthreads();
        if (tid < 16)
            s_h1[tid] = fmaxf(part[0][tid] + part[1][tid] + part[2][tid] + part[3][tid], 0.f);
        __syncthreads();

        const float* w2 = W2 + (size_t)r * 8192;
        int o0 = tid * 2;
        float a0 = 0.f, a1 = 0.f;
        #pragma unroll
        for (int ee = 0; ee < 16; ++ee) {
            float h1e = s_h1[ee];
            float2 ww = *reinterpret_cast<const float2*>(w2 + ee * 512 + o0);
            a0 += h1e * ww.x;
            a1 += h1e * ww.y;
        }
        float2 nz = make_float2(a0, a1);
        float2 zz = make_float2(0.f, 0.f);
        float2* ob = reinterpret_cast<float2*>(outbuf + (size_t)b * 4096);
        #pragma unroll
        for (int v = 0; v < 8; ++v)
            ob[v * 256 + tid] = (v == js) ? nz : zz;
    }
}

extern "C" void kernel_launch(void* const* d_in, const int* in_sizes, int n_in,
                              void* d_out, int out_size, void* d_ws, size_t ws_size,
                              hipStream_t stream) {
    const float* hidden   = (const float*)d_in[0];
    const float* u_var    = (const float*)d_in[1];
    const float* u_rule   = (const float*)d_in[2];
    const float* Wq       = (const float*)d_in[3];
    const float* bq       = (const float*)d_in[4];
    const float* Wk       = (const float*)d_in[5];
    const float* bk       = (const float*)d_in[6];
    const float* rule_emb = (const float*)d_in[7];
    const float* Wq2      = (const float*)d_in[8];
    const float* bq2      = (const float*)d_in[9];
    const float* Wk2      = (const float*)d_in[10];
    const float* bk2      = (const float*)d_in[11];
    const float* W1       = (const float*)d_in[12];
    const float* W2       = (const float*)d_in[13];

    char* ws = (char*)d_ws;
    float* k2f  = (float*)(ws);              // 512 f32
    int*   cnt  = (int*)(ws + 2048);         // 16 i32
    int*   sel  = (int*)(ws + 4096);         // 4096 i32
    int*   list = (int*)(ws + 20480);        // 16*4096 i32
    float* outf = (float*)d_out;

    hipLaunchKernelGGL(k1_kernel, dim3(4096), dim3(256), 0, stream,
                       hidden, u_var, Wq, bq, Wk, bk,
                       rule_emb, Wk2, bk2, k2f, cnt, sel, outf);
    hipLaunchKernelGGL(k2sel_kernel, dim3(512), dim3(256), 0, stream,
                       hidden, u_rule, Wq2, bq2, k2f, sel, outf, cnt, list);
    hipLaunchKernelGGL(k3_kernel, dim3(512), dim3(256), 0, stream,
                       hidden, W1, W2, sel, cnt, list, outf);
}

// Round 8
// 126.097 us; speedup vs baseline: 2.9299x; 1.0059x over previous
//
#include <hip/hip_runtime.h>

#define TEMP 5.656854249492380195f   // sqrt(32)
#define EPSG 1e-10f

#define ROWP 516                     // padded row stride (floats): kills v-stride bank conflicts
#define BSTR (8 * ROWP)              // per-b stride in sh (4128 floats)

// ---------- K1: per-lane full-dot projection + per-wave argmax + hmean -----
// block = 4 b's; wave w: qk = w&1, b-pair bp = w>>1; lane = (v:8, dg:8).
// Each lane accumulates q[v][dg*4..+3] (or k) for 2 b's over the full K=512
// chain -> no shuffle reduce. Weight float4 broadcast across 8 v-lanes and
// reused for 2 b's.
__launch_bounds__(256, 2)
__global__ void k1_kernel(const float* __restrict__ hidden,
                          const float* __restrict__ u_var,
                          const float* __restrict__ Wq,
                          const float* __restrict__ bq,
                          const float* __restrict__ Wk,
                          const float* __restrict__ bk,
                          const float* __restrict__ rule_emb,
                          const float* __restrict__ Wk2,
                          const float* __restrict__ bk2,
                          float* __restrict__ k2f,
                          int* __restrict__ cnt,
                          int* __restrict__ selbuf,
                          float* __restrict__ outbuf) {
    const int tid = threadIdx.x;
    const int b0  = blockIdx.x * 4;

    __shared__ float sh[4 * BSTR];      // 4 padded hidden rows-of-8 (64.5 KB)
    __shared__ float s_qk[4][2][8][32]; // [b][q/k][v][d] (8 KB)

    // merged K0 (block 0 only): k2 = rule_emb@Wk2 + bk2 ; cnt = 0
    if (blockIdx.x == 0) {
        if (tid < 16) cnt[tid] = 0;
        for (int t = tid; t < 512; t += 256) {
            int r = t >> 5, d = t & 31;
            float acc = bk2[d];
            for (int h = 0; h < 64; ++h)
                acc += rule_emb[r * 64 + h] * Wk2[h * 32 + d];
            k2f[t] = acc;
        }
    }

    // ---- stage 4 b's of hidden into padded LDS ----
    {
        const float4* src = reinterpret_cast<const float4*>(hidden + (size_t)b0 * 4096);
        #pragma unroll
        for (int c = 0; c < 16; ++c) {
            int f   = c * 256 + tid;          // float4 flat idx 0..4095
            int bb  = f >> 10;
            int rem = f & 1023;
            int v   = rem >> 7;
            int cc  = rem & 127;
            reinterpret_cast<float4*>(sh)[bb * (BSTR / 4) + v * (ROWP / 4) + cc] = src[f];
        }
    }
    __syncthreads();

    // ---- projection ----
    {
        const int lane = tid & 63;
        const int w    = tid >> 6;        // wave id
        const int qk   = w & 1;
        const int bp   = w >> 1;          // b-pair: handles b0+2*bp, b0+2*bp+1
        const int v    = lane >> 3;
        const int dg   = lane & 7;

        const float* Wsrc = (qk ? Wk : Wq) + dg * 4;
        const float* x0p  = &sh[(bp * 2 + 0) * BSTR + v * ROWP];
        const float* x1p  = &sh[(bp * 2 + 1) * BSTR + v * ROWP];

        float4 acc0 = make_float4(0.f, 0.f, 0.f, 0.f);
        float4 acc1 = make_float4(0.f, 0.f, 0.f, 0.f);

        #pragma unroll 2
        for (int g = 0; g < 128; ++g) {
            const int h = g * 4;
            const float* wrow = Wsrc + (size_t)h * 32;
            float4 w0 = *reinterpret_cast<const float4*>(wrow);
            float4 w1 = *reinterpret_cast<const float4*>(wrow + 32);
            float4 w2 = *reinterpret_cast<const float4*>(wrow + 64);
            float4 w3 = *reinterpret_cast<const float4*>(wrow + 96);
            float4 x0 = *reinterpret_cast<const float4*>(x0p + h);
            float4 x1 = *reinterpret_cast<const float4*>(x1p + h);
            acc0.x += x0.x * w0.x + x0.y * w1.x + x0.z * w2.x + x0.w * w3.x;
            acc0.y += x0.x * w0.y + x0.y * w1.y + x0.z * w2.y + x0.w * w3.y;
            acc0.z += x0.x * w0.z + x0.y * w1.z + x0.z * w2.z + x0.w * w3.z;
            acc0.w += x0.x * w0.w + x0.y * w1.w + x0.z * w2.w + x0.w * w3.w;
            acc1.x += x1.x * w0.x + x1.y * w1.x + x1.z * w2.x + x1.w * w3.x;
            acc1.y += x1.x * w0.y + x1.y * w1.y + x1.z * w2.y + x1.w * w3.y;
            acc1.z += x1.x * w0.z + x1.y * w1.z + x1.z * w2.z + x1.w * w3.z;
            acc1.w += x1.x * w0.w + x1.y * w1.w + x1.z * w2.w + x1.w * w3.w;
        }

        const float* bsrc = (qk ? bk : bq) + dg * 4;
        float4 bias4 = *reinterpret_cast<const float4*>(bsrc);
        float4 r0, r1;
        r0.x = acc0.x + bias4.x; r0.y = acc0.y + bias4.y;
        r0.z = acc0.z + bias4.z; r0.w = acc0.w + bias4.w;
        r1.x = acc1.x + bias4.x; r1.y = acc1.y + bias4.y;
        r1.z = acc1.z + bias4.z; r1.w = acc1.w + bias4.w;
        *reinterpret_cast<float4*>(&s_qk[bp * 2 + 0][qk][v][dg * 4]) = r0;
        *reinterpret_cast<float4*>(&s_qk[bp * 2 + 1][qk][v][dg * 4]) = r1;
    }
    __syncthreads();

    // ---- per-wave: scores + gumbel + 64-way argmax (wave w -> b0+w) ----
    {
        const int w    = tid >> 6;
        const int lane = tid & 63;
        const int b    = b0 + w;
        const int i = lane >> 3, j = lane & 7;
        float s = 0.f;
        #pragma unroll
        for (int d4 = 0; d4 < 8; ++d4) {
            float4 qv = *reinterpret_cast<const float4*>(&s_qk[w][0][i][d4 * 4]);
            float4 kv = *reinterpret_cast<const float4*>(&s_qk[w][1][j][d4 * 4]);
            s += qv.x * kv.x + qv.y * kv.y + qv.z * kv.z + qv.w * kv.w;
        }
        s /= TEMP;
        float u = u_var[(size_t)b * 64 + lane];
        float g = -logf(-logf(u + EPSG) + EPSG);
        float pm = s + g;
        int idx = lane;
        #pragma unroll
        for (int off = 32; off >= 1; off >>= 1) {
            float pv = __shfl_xor(pm, off);
            int   pi = __shfl_xor(idx, off);
            if (pv > pm || (pv == pm && pi < idx)) { pm = pv; idx = pi; }
        }
        if (lane == 0) selbuf[b] = idx;
    }

    // ---- hmean -> outbuf[b][0..511] (scratch; K3 overwrites later) ----
    {
        const int bb   = tid >> 6;
        const int lane = tid & 63;
        const int h0   = lane * 8;
        const float* base = &sh[bb * BSTR];
        float m[8];
        #pragma unroll
        for (int t = 0; t < 8; ++t) m[t] = 0.f;
        #pragma unroll
        for (int v = 0; v < 8; ++v) {
            const float* rp = base + v * ROWP + h0;
            #pragma unroll
            for (int t = 0; t < 8; ++t) m[t] += rp[t];
        }
        float* op = outbuf + (size_t)(b0 + bb) * 4096 + h0;
        float4 o0 = make_float4(m[0] * 0.125f, m[1] * 0.125f, m[2] * 0.125f, m[3] * 0.125f);
        float4 o1 = make_float4(m[4] * 0.125f, m[5] * 0.125f, m[6] * 0.125f, m[7] * 0.125f);
        *reinterpret_cast<float4*>(op)     = o0;
        *reinterpret_cast<float4*>(op + 4) = o1;
    }
}

// ---------- K2: q2 GEMM + rule gumbel argmax + rule buckets ----------------
__launch_bounds__(256, 4)
__global__ void k2sel_kernel(const float* __restrict__ hidden,
                             const float* __restrict__ u_rule,
                             const float* __restrict__ Wq2,
                             const float* __restrict__ bq2,
                             const float* __restrict__ k2f,
                             const int* __restrict__ selbuf,
                             const float* __restrict__ hmeanbuf,
                             int* __restrict__ cnt,
                             int* __restrict__ list) {
    const int tid = threadIdx.x;
    const int b0 = blockIdx.x * 8;

    __shared__ float  s_k2[512];
    __shared__ float  xt[8][256];
    __shared__ float4 part4[4][8][8];
    __shared__ float  s_q2[8][32];
    __shared__ int    s_sel8[8];

    s_k2[tid]       = k2f[tid];
    s_k2[tid + 256] = k2f[tid + 256];
    if (tid < 8) s_sel8[tid] = selbuf[b0 + tid];
    __syncthreads();

    const int d4 = tid & 7, s = tid >> 3;
    float4 acc[8];
    #pragma unroll
    for (int bb = 0; bb < 8; ++bb) acc[bb] = make_float4(0.f, 0.f, 0.f, 0.f);

    for (int kt = 0; kt < 6; ++kt) {
        float4 w[8];
        #pragma unroll
        for (int j = 0; j < 8; ++j)
            w[j] = *reinterpret_cast<const float4*>(Wq2 + (size_t)(kt * 256 + s * 8 + j) * 32 + d4 * 4);
        #pragma unroll
        for (int bb = 0; bb < 8; ++bb) {
            const int b  = b0 + bb;
            const int sv = s_sel8[bb];
            const float* src;
            if (kt < 2)      src = hidden  + ((size_t)b * 8 + (sv & 7))  * 512 + kt * 256;
            else if (kt < 4) src = hidden  + ((size_t)b * 8 + (sv >> 3)) * 512 + (kt - 2) * 256;
            else             src = hmeanbuf + (size_t)b * 4096 + (kt - 4) * 256;
            xt[bb][tid] = src[tid];
        }
        __syncthreads();
        #pragma unroll
        for (int bb = 0; bb < 8; ++bb) {
            #pragma unroll
            for (int j = 0; j < 8; ++j) {
                float x = xt[bb][s * 8 + j];
                acc[bb].x += x * w[j].x;
                acc[bb].y += x * w[j].y;
                acc[bb].z += x * w[j].z;
                acc[bb].w += x * w[j].w;
            }
        }
        __syncthreads();
    }
    #pragma unroll
    for (int off = 8; off < 64; off <<= 1) {
        #pragma unroll
        for (int bb = 0; bb < 8; ++bb) {
            acc[bb].x += __shfl_xor(acc[bb].x, off);
            acc[bb].y += __shfl_xor(acc[bb].y, off);
            acc[bb].z += __shfl_xor(acc[bb].z, off);
            acc[bb].w += __shfl_xor(acc[bb].w, off);
        }
    }
    if ((s & 7) == 0) {
        #pragma unroll
        for (int bb = 0; bb < 8; ++bb) part4[tid >> 6][bb][d4] = acc[bb];
    }
    __syncthreads();
    {
        const int bb = tid >> 5, col = tid & 31;
        float q2 = bq2[col];
        #pragma unroll
        for (int wv = 0; wv < 4; ++wv) {
            const float* pf = reinterpret_cast<const float*>(&part4[wv][bb][col >> 2]);
            q2 += pf[col & 3];
        }
        s_q2[bb][col] = q2;
    }
    __syncthreads();
    if (tid < 128) {
        const int bb = tid >> 4, r = tid & 15;
        const int b = b0 + bb;
        float sc = 0.f;
        #pragma unroll
        for (int d = 0; d < 32; ++d) sc += s_q2[bb][d] * s_k2[r * 32 + d];
        sc /= TEMP;
        float u = u_rule[(size_t)b * 16 + r];
        float g = -logf(-logf(u + EPSG) + EPSG);
        float pm = sc + g;
        int idx = r;
        #pragma unroll
        for (int off = 8; off >= 1; off >>= 1) {
            float pv = __shfl_xor(pm, off, 16);
            int   pi = __shfl_xor(idx, off, 16);
            if (pv > pm || (pv == pm && pi < idx)) { pm = pv; idx = pi; }
        }
        if (r == 0) {
            int pos = atomicAdd(&cnt[idx], 1);
            list[idx * 4096 + pos] = b;
        }
    }
}

// ---------- K3: rule-bucketed MLP + full output write ----------------------
__launch_bounds__(256, 2)
__global__ void k3_kernel(const float* __restrict__ hidden,
                          const float* __restrict__ W1,
                          const float* __restrict__ W2,
                          const int* __restrict__ selbuf,
                          const int* __restrict__ cnt,
                          const int* __restrict__ list,
                          float* __restrict__ outbuf) {
    const int tid = threadIdx.x;
    const int r   = blockIdx.x & 15;       // rule
    const int c   = blockIdx.x >> 4;       // chunk 0..31

    __shared__ float w1s[16384];           // W1[r] as [row*16+e] (64 KB)
    __shared__ float comb[1024];
    __shared__ float part[4][16];
    __shared__ float s_h1[16];

    #pragma unroll
    for (int i = 0; i < 16; ++i) {
        int idx = i * 1024 + tid * 4;
        *reinterpret_cast<float4*>(&w1s[idx]) =
            *reinterpret_cast<const float4*>(W1 + (size_t)r * 16384 + idx);
    }
    const int n = cnt[r];
    __syncthreads();

    const int e  = tid & 15;
    const int sl = tid >> 4;

    for (int idx = c; idx < n; idx += 32) {
        const int b  = list[r * 4096 + idx];
        const int sv = selbuf[b];
        const int js = sv & 7, cs = sv >> 3;

        {
            const float4* h4 = reinterpret_cast<const float4*>(hidden);
            float4 v;
            if (tid < 128) v = h4[((size_t)b * 8 + js) * 128 + tid];
            else           v = h4[((size_t)b * 8 + cs) * 128 + (tid - 128)];
            *reinterpret_cast<float4*>(&comb[tid * 4]) = v;
        }
        __syncthreads();

        float a = 0.f;
        for (int i = 0; i < 64; ++i) {
            int rr = i * 16 + sl;
            a += comb[rr] * w1s[rr * 16 + e];
        }
        a += __shfl_xor(a, 16);
        a += __shfl_xor(a, 32);
        if ((sl & 3) == 0) part[sl >> 2][e] = a;
        __syncthreads();
        if (tid < 16)
            s_h1[tid] = fmaxf(part[0][tid] + part[1][tid] + part[2][tid] + part[3][tid], 0.f);
        __syncthreads();

        const float* w2 = W2 + (size_t)r * 8192;
        int o0 = tid * 2;
        float a0 = 0.f, a1 = 0.f;
        #pragma unroll
        for (int ee = 0; ee < 16; ++ee) {
            float h1e = s_h1[ee];
            float2 ww = *reinterpret_cast<const float2*>(w2 + ee * 512 + o0);
            a0 += h1e * ww.x;
            a1 += h1e * ww.y;
        }
        float2 nz = make_float2(a0, a1);
        float2 zz = make_float2(0.f, 0.f);
        float2* ob = reinterpret_cast<float2*>(outbuf + (size_t)b * 4096);
        #pragma unroll
        for (int v = 0; v < 8; ++v)
            ob[v * 256 + tid] = (v == js) ? nz : zz;
    }
}

extern "C" void kernel_launch(void* const* d_in, const int* in_sizes, int n_in,
                              void* d_out, int out_size, void* d_ws, size_t ws_size,
                              hipStream_t stream) {
    const float* hidden   = (const float*)d_in[0];
    const float* u_var    = (const float*)d_in[1];
    const float* u_rule   = (const float*)d_in[2];
    const float* Wq       = (const float*)d_in[3];
    const float* bq       = (const float*)d_in[4];
    const float* Wk       = (const float*)d_in[5];
    const float* bk       = (const float*)d_in[6];
    const float* rule_emb = (const float*)d_in[7];
    const float* Wq2      = (const float*)d_in[8];
    const float* bq2      = (const float*)d_in[9];
    const float* Wk2      = (const float*)d_in[10];
    const float* bk2      = (const float*)d_in[11];
    const float* W1       = (const float*)d_in[12];
    const float* W2       = (const float*)d_in[13];

    char* ws = (char*)d_ws;
    float* k2f  = (float*)(ws);              // 512 f32
    int*   cnt  = (int*)(ws + 2048);         // 16 i32
    int*   sel  = (int*)(ws + 4096);         // 4096 i32
    int*   list = (int*)(ws + 20480);        // 16*4096 i32
    float* outf = (float*)d_out;

    hipLaunchKernelGGL(k1_kernel, dim3(1024), dim3(256), 0, stream,
                       hidden, u_var, Wq, bq, Wk, bk,
                       rule_emb, Wk2, bk2, k2f, cnt, sel, outf);
    hipLaunchKernelGGL(k2sel_kernel, dim3(512), dim3(256), 0, stream,
                       hidden, u_rule, Wq2, bq2, k2f, sel, outf, cnt, list);
    hipLaunchKernelGGL(k3_kernel, dim3(512), dim3(256), 0, stream,
                       hidden, W1, W2, sel, cnt, list, outf);
}